// Round 4
// baseline (434.577 us; speedup 1.0000x reference)
//
#include <hip/hip_runtime.h>
#include <cstdint>
#include <cstddef>

#define BATCH 1024
#define S1 25
#define S2 10
#define FDIM 256
#define HDIM 128
#define NCLS 41
#define MAXDEG 128

typedef __attribute__((ext_vector_type(8))) short bf16x8;
typedef __attribute__((ext_vector_type(4))) float f32x4;

// ---------------- Threefry-2x32 (bit-exact vs JAX partitionable; r1-verified) --------
__host__ __device__ static inline void tf2x32(uint32_t k0, uint32_t k1,
                                              uint32_t c0, uint32_t c1,
                                              uint32_t& o0, uint32_t& o1) {
  const uint32_t ks2 = k0 ^ k1 ^ 0x1BD11BDAu;
  uint32_t x0 = c0 + k0, x1 = c1 + k1;
#define TFR(r) { x0 += x1; x1 = (x1 << (r)) | (x1 >> (32 - (r))); x1 ^= x0; }
  TFR(13) TFR(15) TFR(26) TFR(6)
  x0 += k1;  x1 += ks2 + 1u;
  TFR(17) TFR(29) TFR(16) TFR(24)
  x0 += ks2; x1 += k0 + 2u;
  TFR(13) TFR(15) TFR(26) TFR(6)
  x0 += k0;  x1 += k1 + 3u;
  TFR(17) TFR(29) TFR(16) TFR(24)
  x0 += k1;  x1 += ks2 + 4u;
  TFR(13) TFR(15) TFR(26) TFR(6)
  x0 += ks2; x1 += k0 + 5u;
#undef TFR
  o0 = x0; o1 = x1;
}

__device__ static inline uint32_t rand_bits_at(uint32_t kb0, uint32_t kb1, uint32_t j) {
  uint32_t o0, o1;
  tf2x32(kb0, kb1, 0u, j, o0, o1);
  return o0 ^ o1;
}

__device__ static inline ushort f2bf(float x) {       // RNE, bit-identical to r2/r3
  uint32_t u = __float_as_uint(x);
  return (ushort)((u + 0x7fffu + ((u >> 16) & 1u)) >> 16);
}
__device__ static inline float bf2f(ushort u) {
  return __uint_as_float(((uint32_t)u) << 16);
}

// ================= K0: W1 -> bf16 transposed WbT[n][k]; n<128: Ws1 col, else Wn1 =====
__global__ __launch_bounds__(256)
void wprep_kernel(const float* __restrict__ Ws1, const float* __restrict__ Wn1,
                  ushort* __restrict__ WbT) {
  const int n = blockIdx.x;            // 0..255
  const int k = threadIdx.x;           // 0..255
  const float* W = (n < HDIM) ? Ws1 : Wn1;
  const int c = n & (HDIM - 1);
  WbT[(size_t)n * FDIM + k] = f2bf(W[(size_t)k * HDIM + c]);
}

// ================= K1: dense projection GEMM FW = feat @ [Ws1|Wn1]  (bf16 out) =======
// 3125 blocks x 256 thr. Tile: 64 rows x 256 cols, K=256 in 8 steps of 32.
// MFMA 16x16x32 bf16 (r2/r3-verified fragment mapping). A fp32->bf16 in staging.
__global__ __launch_bounds__(256, 2)
void proj_kernel(const float* __restrict__ feat, const ushort* __restrict__ WbT,
                 ushort* __restrict__ FW) {
  const int m0 = blockIdx.x * 64;
  const int tid = threadIdx.x;
  const int wave = tid >> 6;
  const int lane = tid & 63;
  const int lq = lane >> 4;
  const int lr = lane & 15;

  __shared__ ushort As[64][40];     // [m][k] +8 pad
  __shared__ ushort Bs[256][40];    // [n][k] +8 pad
  __shared__ float  Cs[64][132];    // epilogue staging (two passes of 128 cols)

  f32x4 acc[4][4];
#pragma unroll
  for (int rt = 0; rt < 4; ++rt)
#pragma unroll
    for (int ct = 0; ct < 4; ++ct) acc[rt][ct] = (f32x4)(0.f);

  for (int k0 = 0; k0 < FDIM; k0 += 32) {
    // stage A: 64 rows x 32 k (fp32 -> bf16)
    {
      const int row = tid >> 2, kc = (tid & 3) * 8;
      const float* rp = feat + (size_t)(m0 + row) * FDIM + k0 + kc;
      float4 v0 = *(const float4*)rp;
      float4 v1 = *(const float4*)(rp + 4);
      union { ushort u[8]; int4 v; } pk;
      pk.u[0] = f2bf(v0.x); pk.u[1] = f2bf(v0.y); pk.u[2] = f2bf(v0.z); pk.u[3] = f2bf(v0.w);
      pk.u[4] = f2bf(v1.x); pk.u[5] = f2bf(v1.y); pk.u[6] = f2bf(v1.z); pk.u[7] = f2bf(v1.w);
      *(int4*)&As[row][kc] = pk.v;
    }
    // stage B: 256 n x 32 k bf16 (4 x int4 per thread-round)
#pragma unroll
    for (int i = 0; i < 4; ++i) {
      const int idx = tid + i * 256;
      const int n = idx >> 2, kc = (idx & 3) * 8;
      *(int4*)&Bs[n][kc] = *(const int4*)(WbT + (size_t)n * FDIM + k0 + kc);
    }
    __syncthreads();

    bf16x8 af[4];
#pragma unroll
    for (int rt = 0; rt < 4; ++rt)
      af[rt] = *(const bf16x8*)&As[rt * 16 + lr][lq * 8];
#pragma unroll
    for (int ct = 0; ct < 4; ++ct) {
      bf16x8 bf = *(const bf16x8*)&Bs[wave * 64 + ct * 16 + lr][lq * 8];
#pragma unroll
      for (int rt = 0; rt < 4; ++rt)
        acc[rt][ct] = __builtin_amdgcn_mfma_f32_16x16x32_bf16(af[rt], bf, acc[rt][ct], 0, 0, 0);
    }
    __syncthreads();
  }

  // epilogue: two passes of 128 cols through Cs, coalesced bf16 stores
#pragma unroll
  for (int p = 0; p < 2; ++p) {
    if ((wave >> 1) == p) {
      const int cb = (wave & 1) * 64;
#pragma unroll
      for (int rt = 0; rt < 4; ++rt)
#pragma unroll
        for (int ct = 0; ct < 4; ++ct)
#pragma unroll
          for (int r = 0; r < 4; ++r)
            Cs[rt * 16 + lq * 4 + r][cb + ct * 16 + lr] = acc[rt][ct][r];
    }
    __syncthreads();
    {
      const int row = tid >> 2, c0 = (tid & 3) * 32;
      ushort* dst = FW + (size_t)(m0 + row) * FDIM + p * HDIM + c0;
#pragma unroll
      for (int j = 0; j < 32; j += 8) {
        union { ushort u[8]; int4 v; } pk;
#pragma unroll
        for (int q = 0; q < 8; ++q) pk.u[q] = f2bf(Cs[row][c0 + j + q]);
        *(int4*)(dst + j) = pk.v;
      }
    }
    __syncthreads();
  }
}

// ================= K2: per-b sampling + h1 agg + h0 + layer2 + head ==================
// 1024 blocks x 256 thr. All intermediates in LDS; no atomics; writes out directly.
__global__ __launch_bounds__(256)
void agg_kernel(const int* __restrict__ node_ids, const float* __restrict__ feat,
                const int* __restrict__ adj, const ushort* __restrict__ FW,
                const float* __restrict__ Ws1, const float* __restrict__ Wn1,
                const float* __restrict__ Ws2, const float* __restrict__ Wn2,
                const float* __restrict__ Wp, const float* __restrict__ bp,
                float* __restrict__ out,
                uint32_t kb1_0, uint32_t kb1_1, uint32_t kb2_0, uint32_t kb2_1) {
  const int b = blockIdx.x;
  const int t = threadIdx.x;
  const int wave = t >> 6, lane = t & 63;

  __shared__ int   h1r[S1];
  __shared__ int   h2r[S1 * S2];
  __shared__ float f0s[FDIM];
  __shared__ float redA[4][FDIM];   // h1 partials
  __shared__ float redB[4][FDIM];   // n1m partials
  __shared__ float h1m[FDIM], n1m[FDIM], h0s[FDIM], hhn[FDIM];
  __shared__ float lgs[NCLS];
  __shared__ float smred[4];
  __shared__ float smax[2];
  __shared__ int   nid_s;

  if (t == 0) nid_s = node_ids[b];
  __syncthreads();
  const int nid = nid_s;
  if (t < S1) {
    uint32_t c1 = rand_bits_at(kb1_0, kb1_1, (uint32_t)(b * S1 + t)) & (MAXDEG - 1);
    h1r[t] = adj[(size_t)nid * MAXDEG + c1];
  }
  if (t >= 64 && t < 128)
    ((float4*)f0s)[t - 64] = ((const float4*)(feat + (size_t)nid * FDIM))[t - 64];
  __syncthreads();
  if (t < S1 * S2) {
    uint32_t c2 = rand_bits_at(kb2_0, kb2_1, (uint32_t)(b * S1 * S2 + t)) & (MAXDEG - 1);
    h2r[t] = adj[(size_t)h1r[t / S2] * MAXDEG + c2];
  }
  __syncthreads();

  // per-wave: h1 = relu([FW.self ; mean10 FW.neigh]) accumulated over l; n1m fp32
  float sx = 0.f, sy = 0.f, nx = 0.f, ny = 0.f;
  float4 a1 = make_float4(0.f, 0.f, 0.f, 0.f);
  for (int l = wave; l < S1; l += 4) {
    const int rs = h1r[l];
    ushort2 sv = *(const ushort2*)(FW + (size_t)rs * FDIM + lane * 2);
    float nbx = 0.f, nby = 0.f;
    const int* hr = &h2r[l * S2];
#pragma unroll
    for (int s = 0; s < S2; ++s) {
      const int rn = hr[s];
      ushort2 nv = *(const ushort2*)(FW + (size_t)rn * FDIM + HDIM + lane * 2);
      nbx += bf2f(nv.x); nby += bf2f(nv.y);
    }
    sx += fmaxf(bf2f(sv.x), 0.f);
    sy += fmaxf(bf2f(sv.y), 0.f);
    nx += fmaxf(nbx * (1.f / S2), 0.f);
    ny += fmaxf(nby * (1.f / S2), 0.f);
    float4 fv = ((const float4*)(feat + (size_t)rs * FDIM))[lane];
    a1.x += fv.x; a1.y += fv.y; a1.z += fv.z; a1.w += fv.w;
  }
  redA[wave][lane * 2]            = sx;
  redA[wave][lane * 2 + 1]        = sy;
  redA[wave][HDIM + lane * 2]     = nx;
  redA[wave][HDIM + lane * 2 + 1] = ny;
  ((float4*)redB[wave])[lane] = a1;
  __syncthreads();
  {
    float v = (redA[0][t] + redA[1][t]) + (redA[2][t] + redA[3][t]);
    h1m[t] = v * (1.f / S1);
    float u = (redB[0][t] + redB[1][t]) + (redB[2][t] + redB[3][t]);
    n1m[t] = u * (1.f / S1);
  }
  __syncthreads();

  // h0 = relu([f0@Ws1 ; n1m@Wn1])  (fp32 exact path)
  {
    const int h = t >> 7, c = t & 127;
    const float* A = h ? n1m : f0s;
    const float* W = h ? Wn1 : Ws1;
    float acc = 0.f;
    for (int k = 0; k < FDIM; k += 4) {
      acc += A[k]     * W[(size_t)k       * HDIM + c]
           + A[k + 1] * W[(size_t)(k + 1) * HDIM + c]
           + A[k + 2] * W[(size_t)(k + 2) * HDIM + c]
           + A[k + 3] * W[(size_t)(k + 3) * HDIM + c];
    }
    h0s[t] = fmaxf(acc, 0.f);
  }
  __syncthreads();

  // hh = [h0@Ws2 ; h1m@Wn2]
  float hv;
  {
    const int h = t >> 7, c = t & 127;
    const float* A = h ? h1m : h0s;
    const float* W = h ? Wn2 : Ws2;
    float acc = 0.f;
    for (int k = 0; k < FDIM; k += 4) {
      acc += A[k]     * W[(size_t)k       * HDIM + c]
           + A[k + 1] * W[(size_t)(k + 1) * HDIM + c]
           + A[k + 2] * W[(size_t)(k + 2) * HDIM + c]
           + A[k + 3] * W[(size_t)(k + 3) * HDIM + c];
    }
    hv = acc;
  }
  // l2 normalize
  float ss = hv * hv;
#pragma unroll
  for (int off = 32; off; off >>= 1) ss += __shfl_xor(ss, off, 64);
  if (lane == 0) smred[wave] = ss;
  __syncthreads();
  if (t == 0)
    smax[0] = rsqrtf(fmaxf(smred[0] + smred[1] + smred[2] + smred[3], 1e-12f));
  __syncthreads();
  hhn[t] = hv * smax[0];
  __syncthreads();

  // logits + softmax
  if (t < NCLS) {
    float acc = bp[t];
    for (int k = 0; k < 2 * HDIM; ++k) acc += hhn[k] * Wp[(size_t)k * NCLS + t];
    lgs[t] = acc;
  }
  __syncthreads();
  if (t == 0) {
    float m = -1e30f;
    for (int i = 0; i < NCLS; ++i) m = fmaxf(m, lgs[i]);
    float s = 0.f;
    for (int i = 0; i < NCLS; ++i) s += expf(lgs[i] - m);
    smax[0] = m; smax[1] = s;
  }
  __syncthreads();
  if (t < NCLS) out[(size_t)b * NCLS + t] = expf(lgs[t] - smax[0]) / smax[1];
}

// ================= launch ============================================================
extern "C" void kernel_launch(void* const* d_in, const int* in_sizes, int n_in,
                              void* d_out, int out_size, void* d_ws, size_t ws_size,
                              hipStream_t stream) {
  const int*   node_ids = (const int*)d_in[0];
  const float* features = (const float*)d_in[1];
  const int*   adj      = (const int*)d_in[2];
  const float* Ws1      = (const float*)d_in[3];
  const float* Wn1      = (const float*)d_in[4];
  const float* Ws2      = (const float*)d_in[5];
  const float* Wn2      = (const float*)d_in[6];
  const float* Wp       = (const float*)d_in[7];
  const float* bp       = (const float*)d_in[8];
  float* out = (float*)d_out;

  char* ws = (char*)d_ws;
  ushort* WbT = (ushort*)(ws + 0);          // 256x256 bf16 (128 KB)
  ushort* FW  = (ushort*)(ws + 131072);     // 200000x256 bf16 (102.4 MB)

  // JAX threefry key chain (bit-exact, r1-verified)
  uint32_t k1_0, k1_1, k2_0, k2_1, kb1_0, kb1_1, kb2_0, kb2_1;
  tf2x32(0u, 42u, 0u, 0u, k1_0, k1_1);
  tf2x32(0u, 42u, 0u, 1u, k2_0, k2_1);
  tf2x32(k1_0, k1_1, 0u, 1u, kb1_0, kb1_1);
  tf2x32(k2_0, k2_1, 0u, 1u, kb2_0, kb2_1);

  wprep_kernel<<<256, 256, 0, stream>>>(Ws1, Wn1, WbT);
  proj_kernel<<<200000 / 64, 256, 0, stream>>>(features, WbT, FW);
  agg_kernel<<<BATCH, 256, 0, stream>>>(node_ids, features, adj, FW,
                                        Ws1, Wn1, Ws2, Wn2, Wp, bp, out,
                                        kb1_0, kb1_1, kb2_0, kb2_1);
}